// Round 17
// baseline (34.448 us; speedup 1.0000x reference)
//
#include <hip/hip_runtime.h>
#include <hip/hip_fp16.h>
#include <math.h>

// PerVertQuaternion, round 17: 3-dispatch pipeline (sort -> transpose ->
// countfinish).
//
// R16: fast math cut finish 15.5 -> ~7us (41 -> 32.8 total). This round
// merges count into finish -- viable now (unlike R14) because HoffT exists:
// block b's count walk is a CONTIGUOUS 2KB descriptor row, and the two
// boundary rows (base-1, base-2) need only one more contiguous row walk
// filtered for 2 residues. Deletes the count dispatch + cntA round-trip.
//
// Session laws: scattered global WRITES catastrophic (19G sectors/s,
// cross-XCD write-through); scattered READS cheap when L2-resident;
// rocclr memset slow; grid.sync ~30us (kernel boundaries cheaper);
// dedup by base vertex (identical faces -> count*w); precise sqrt/div are
// ~10-op sequences -- use native v_rsq/v_rcp/v_sqrt when tolerance allows.

#define BS     256     // bases per bucket
#define NBMAX  2048    // max buckets (V <= 524288)
#define NBLK1  512     // sort chunks
#define CHMAX  2048    // max faces per chunk (F <= 1,048,576)

__device__ __forceinline__ float fast_rsqrt(float x) {
#if __has_builtin(__builtin_amdgcn_rsqf)
    return __builtin_amdgcn_rsqf(x);
#else
    return rsqrtf(x);
#endif
}
__device__ __forceinline__ float fast_rcp(float x) {
#if __has_builtin(__builtin_amdgcn_rcpf)
    return __builtin_amdgcn_rcpf(x);
#else
    return 1.0f / x;
#endif
}
__device__ __forceinline__ float fast_sqrt(float x) {
#if __has_builtin(__builtin_amdgcn_sqrtf)
    return __builtin_amdgcn_sqrtf(x);
#else
    return sqrtf(x);
#endif
}

struct V3 { float x, y, z; };

__device__ __forceinline__ V3 v3sub(const V3& a, const V3& b) {
    return V3{a.x - b.x, a.y - b.y, a.z - b.z};
}
__device__ __forceinline__ V3 v3cross(const V3& a, const V3& b) {
    return V3{a.y * b.z - a.z * b.y,
              a.z * b.x - a.x * b.z,
              a.x * b.y - a.y * b.x};
}
__device__ __forceinline__ float v3dot(const V3& a, const V3& b) {
    return a.x * b.x + a.y * b.y + a.z * b.z;
}
__device__ __forceinline__ V3 loadv(const float* __restrict__ p, int i) {
    return V3{p[3 * i], p[3 * i + 1], p[3 * i + 2]};
}

// Orthonormal frame via n ⟂ d / X ⟂ d algebra; returns n2 for area reuse.
__device__ __forceinline__ float frame_fast(V3 a, V3 b, V3 c,
                                            V3& X, V3& Y, V3& Z) {
    V3 d = v3sub(b, a);
    V3 e = v3sub(c, a);
    V3 n = v3cross(d, e);
    float n2 = v3dot(n, n);
    float d2 = v3dot(d, d);
    float inv_d = fast_rsqrt(fmaxf(d2, 1e-24f));
    float inv_n = fast_rsqrt(fmaxf(n2, 1e-24f));
    V3 cdn = v3cross(d, n);
    float sX = inv_n * inv_d;           // |cross(d, n_hat)| == |d|
    X = V3{cdn.x * sX, cdn.y * sX, cdn.z * sX};
    V3 cdx = v3cross(d, X);             // |cross(d, X)| == |d|
    Y = V3{cdx.x * inv_d, cdx.y * inv_d, cdx.z * inv_d};
    Z = V3{d.x * inv_d, d.y * inv_d, d.z * inv_d};
    return n2;
}

__device__ __forceinline__ void face_core(V3 ca, V3 cb, V3 cc,
                                          V3 da, V3 db, V3 dc,
                                          float& w0, float& w1, float& w2, float& w3) {
    V3 Xc, Yc, Zc, Xd, Yd, Zd;
    float n2c = frame_fast(ca, cb, cc, Xc, Yc, Zc);
    (void)frame_fast(da, db, dc, Xd, Yd, Zd);

    // area = |cross(cc-cb,ca-cb)|/2 == |cross(cb-ca,cc-ca)|/2 = sqrt(n2c)/2
    float area = 0.5f * fast_sqrt(n2c);

    // Rot = R_deform * R_cano^T (orthonormal frames -> inv == transpose)
    float Rd[3][3] = {{Xd.x, Yd.x, Zd.x}, {Xd.y, Yd.y, Zd.y}, {Xd.z, Yd.z, Zd.z}};
    float Rc[3][3] = {{Xc.x, Yc.x, Zc.x}, {Xc.y, Yc.y, Zc.y}, {Xc.z, Yc.z, Zc.z}};
    float m00 = Rd[0][0]*Rc[0][0] + Rd[0][1]*Rc[0][1] + Rd[0][2]*Rc[0][2];
    float m01 = Rd[0][0]*Rc[1][0] + Rd[0][1]*Rc[1][1] + Rd[0][2]*Rc[1][2];
    float m02 = Rd[0][0]*Rc[2][0] + Rd[0][1]*Rc[2][1] + Rd[0][2]*Rc[2][2];
    float m10 = Rd[1][0]*Rc[0][0] + Rd[1][1]*Rc[0][1] + Rd[1][2]*Rc[0][2];
    float m11 = Rd[1][0]*Rc[1][0] + Rd[1][1]*Rc[1][1] + Rd[1][2]*Rc[1][2];
    float m12 = Rd[1][0]*Rc[2][0] + Rd[1][1]*Rc[2][1] + Rd[1][2]*Rc[2][2];
    float m20 = Rd[2][0]*Rc[0][0] + Rd[2][1]*Rc[0][1] + Rd[2][2]*Rc[0][2];
    float m21 = Rd[2][0]*Rc[1][0] + Rd[2][1]*Rc[1][1] + Rd[2][2]*Rc[1][2];
    float m22 = Rd[2][0]*Rc[2][0] + Rd[2][1]*Rc[2][1] + Rd[2][2]*Rc[2][2];

    // argmax over qa == argmax over t; qa_best^2 == t_best -> ONE sqrt.
    float t0 = 1.0f + m00 + m11 + m22;
    float t1 = 1.0f + m00 - m11 - m22;
    float t2 = 1.0f - m00 + m11 - m22;
    float t3 = 1.0f - m00 - m11 + m22;
    int best = 0; float tb = t0;
    if (t1 > tb) { best = 1; tb = t1; }
    if (t2 > tb) { best = 2; tb = t2; }
    if (t3 > tb) { best = 3; tb = t3; }
    float qb = fast_sqrt(tb);

    float q0, q1, q2, q3;
    if (best == 0)      { q0 = tb;      q1 = m21-m12; q2 = m02-m20; q3 = m10-m01; }
    else if (best == 1) { q0 = m21-m12; q1 = tb;      q2 = m10+m01; q3 = m02+m20; }
    else if (best == 2) { q0 = m02-m20; q1 = m10+m01; q2 = tb;      q3 = m12+m21; }
    else                { q0 = m10-m01; q1 = m20+m02; q2 = m21+m12; q3 = tb;      }
    float scale = area * 0.5f * fast_rcp(fmaxf(qb, 0.1f));
    w0 = q0 * scale; w1 = q1 * scale; w2 = q2 * scale; w3 = q3 * scale;
}

__device__ __forceinline__ void face_math(const float* __restrict__ mesh,
                                          const float* __restrict__ cano,
                                          int i0, int i1, int i2,
                                          float& w0, float& w1, float& w2, float& w3) {
    face_core(loadv(cano, i0), loadv(cano, i1), loadv(cano, i2),
              loadv(mesh, i0), loadv(mesh, i1), loadv(mesh, i2),
              w0, w1, w2, w3);
}

__device__ __forceinline__ bool is_structured(int i0, int i1, int i2, int V) {
    int e1 = (i0 + 1 < V) ? i0 + 1 : i0 + 1 - V;
    int e2 = (i0 + 2 < V) ? i0 + 2 : i0 + 2 - V;
    return (i1 == e1) & (i2 == e2);
}

// ---------------- P1: counting sort -> residue bytes, block-major -----------
__global__ __launch_bounds__(1024)
void sort_kernel(const int* __restrict__ faces,
                 unsigned int* __restrict__ Hoff,      // [NBLK1][NBMAX] off|cnt<<16
                 unsigned char* __restrict__ S1,       // [NBLK1][CHUNKF] residues
                 int* __restrict__ unstCnt,            // [NBLK1]
                 int* __restrict__ unstList,           // [NBLK1][CHUNKF]
                 int F, int V, int NB, int CHUNKF) {
    __shared__ int h[NBMAX];
    __shared__ int off[NBMAX];
    __shared__ int cnt2[NBMAX];
    __shared__ int S0[CHMAX];
    __shared__ int wsum[16];
    __shared__ int unstC;

    int tid = threadIdx.x;
    for (int b = tid; b < NB; b += 1024) { h[b] = 0; cnt2[b] = 0; }
    if (tid == 0) unstC = 0;
    __syncthreads();

    int beg = blockIdx.x * CHUNKF;
    int end = min(F, beg + CHUNKF);

    for (int f = beg + tid; f < end; f += 1024) {
        int i0 = faces[3 * f + 0];
        int i1 = faces[3 * f + 1];
        int i2 = faces[3 * f + 2];
        if (is_structured(i0, i1, i2, V)) {
            S0[f - beg] = i0;
            atomicAdd(&h[i0 >> 8], 1);
        } else {
            S0[f - beg] = -1;
            int p = atomicAdd(&unstC, 1);
            unstList[(size_t)blockIdx.x * CHUNKF + p] = f;
        }
    }
    __syncthreads();

    {
        int e0 = (2 * tid < NB)     ? h[2 * tid]     : 0;
        int e1 = (2 * tid + 1 < NB) ? h[2 * tid + 1] : 0;
        int mysum = e0 + e1;
        int lane = tid & 63, wid = tid >> 6;
        int inc = mysum;
        #pragma unroll
        for (int d = 1; d < 64; d <<= 1) {
            int up = __shfl_up(inc, d);
            if (lane >= d) inc += up;
        }
        if (lane == 63) wsum[wid] = inc;
        __syncthreads();
        if (tid == 0) {
            int run = 0;
            #pragma unroll
            for (int i = 0; i < 16; ++i) { int x = wsum[i]; wsum[i] = run; run += x; }
        }
        __syncthreads();
        int excl = wsum[wid] + inc - mysum;
        if (2 * tid < NBMAX)     off[2 * tid]     = excl;
        if (2 * tid + 1 < NBMAX) off[2 * tid + 1] = excl + e0;
    }
    __syncthreads();

    for (int b = tid; b < NB; b += 1024)
        Hoff[(size_t)blockIdx.x * NBMAX + b] =
            (unsigned int)off[b] | ((unsigned int)h[b] << 16);
    if (tid == 0) unstCnt[blockIdx.x] = unstC;

    unsigned char* S1blk = S1 + (size_t)blockIdx.x * CHUNKF;
    for (int j = tid; j < end - beg; j += 1024) {
        int i0 = S0[j];
        if (i0 >= 0) {
            int b = i0 >> 8;
            int p = atomicAdd(&cnt2[b], 1);
            S1blk[off[b] + p] = (unsigned char)(i0 & 0xFF);
        }
    }
}

// ---------------- P2: tiled transpose Hoff -> HoffT -------------------------
__global__ __launch_bounds__(1024)
void transpose_kernel(const unsigned int* __restrict__ Hoff,
                      unsigned int* __restrict__ HoffT, int NB) {
    __shared__ unsigned int tile[64][65];
    int bx = blockIdx.x * 64;
    int by = blockIdx.y * 64;
    int tx = threadIdx.x;
    int ty = threadIdx.y;
    #pragma unroll
    for (int k = 0; k < 4; ++k) {
        int r = by + ty + k * 16;
        int c = bx + tx;
        tile[ty + k * 16][tx] = (c < NB) ? Hoff[(size_t)r * NBMAX + c] : 0u;
    }
    __syncthreads();
    #pragma unroll
    for (int k = 0; k < 4; ++k) {
        int rowT = bx + ty + k * 16;
        int colT = by + tx;
        if (rowT < NB)
            HoffT[(size_t)rowT * NBLK1 + colT] = tile[tx][ty + k * 16];
    }
}

// ---------------- P3: fused count + math + window sum + normalize -----------
__global__ __launch_bounds__(256)
void countfinish_kernel(const float* __restrict__ mesh,
                        const float* __restrict__ cano,
                        const unsigned int* __restrict__ HoffT,
                        const unsigned char* __restrict__ S1,
                        const int* __restrict__ unstCnt,
                        const int* __restrict__ unstList,
                        const int* __restrict__ faces,
                        float* __restrict__ out,
                        int V, int NB, int CHUNKF) {
    __shared__ unsigned int cnt_l[BS];
    __shared__ unsigned int cntB[2];     // counts for rows base-2, base-1
    __shared__ float4 Tw[BS + 2];
    __shared__ float Ew[BS][4];
    __shared__ int anyU;

    int b = blockIdx.x;
    int base = b * BS;
    int t = threadIdx.x;

    cnt_l[t] = 0;
    if (t < 2) cntB[t] = 0;
    if (t == 0) anyU = 0;
    __syncthreads();
    {   // any unstructured faces anywhere? (2KB, L2-broadcast)
        int u = unstCnt[t] | unstCnt[t + 256];
        if (u) atomicOr(&anyU, 1);
    }

    // own-bucket count: contiguous HoffT row b (2 descriptors per thread)
    for (int r = t; r < NBLK1; r += 256) {
        unsigned int pc = HoffT[(size_t)b * NBLK1 + r];
        int start = (int)(pc & 0xFFFFu);
        int cnt   = (int)(pc >> 16);
        const unsigned char* run = S1 + (size_t)r * CHUNKF + start;
        for (int j = 0; j < cnt; ++j)
            atomicAdd(&cnt_l[run[j]], 1u);
    }

    // boundary rows base-2 (cntB[0]), base-1 (cntB[1]): contiguous row walks
    int row0 = base - 2; if (row0 < 0) row0 += V;
    int row1 = base - 1; if (row1 < 0) row1 += V;
    int bb0 = row0 >> 8, bb1 = row1 >> 8;
    unsigned char res0 = (unsigned char)(row0 & 255);
    unsigned char res1 = (unsigned char)(row1 & 255);
    for (int r = t; r < NBLK1; r += 256) {
        unsigned int pc = HoffT[(size_t)bb0 * NBLK1 + r];
        int start = (int)(pc & 0xFFFFu);
        int cnt   = (int)(pc >> 16);
        const unsigned char* run = S1 + (size_t)r * CHUNKF + start;
        for (int j = 0; j < cnt; ++j) {
            unsigned char x = run[j];
            if (x == res0) atomicAdd(&cntB[0], 1u);
            if (bb1 == bb0 && x == res1) atomicAdd(&cntB[1], 1u);
        }
    }
    if (bb1 != bb0) {
        for (int r = t; r < NBLK1; r += 256) {
            unsigned int pc = HoffT[(size_t)bb1 * NBLK1 + r];
            int start = (int)(pc & 0xFFFFu);
            int cnt   = (int)(pc >> 16);
            const unsigned char* run = S1 + (size_t)r * CHUNKF + start;
            for (int j = 0; j < cnt; ++j)
                if (run[j] == res1) atomicAdd(&cntB[1], 1u);
        }
    }
    __syncthreads();

    // per-row dedup'd math: Tw[j] = count * w for row base-2+j
    int rows = min(BS, V - base);
    for (int j = t; j < rows + 2; j += 256) {
        int row = base - 2 + j;
        if (row < 0) row += V;
        unsigned int c = (j == 0) ? cntB[0] : (j == 1) ? cntB[1] : cnt_l[j - 2];
        float4 res = make_float4(0.f, 0.f, 0.f, 0.f);
        if (c > 0) {
            int i1 = (row + 1 < V) ? row + 1 : row + 1 - V;
            int i2 = (row + 2 < V) ? row + 2 : row + 2 - V;
            float w0, w1, w2, w3;
            face_math(mesh, cano, row, i1, i2, w0, w1, w2, w3);
            float fc = (float)c;
            res = make_float4(w0 * fc, w1 * fc, w2 * fc, w3 * fc);
        }
        Tw[j] = res;
    }
    __syncthreads();

    if (anyU) {   // rare/never path: unstructured fixup via LDS
        Ew[t][0] = Ew[t][1] = Ew[t][2] = Ew[t][3] = 0.f;
        __syncthreads();
        for (int blk = 0; blk < NBLK1; ++blk) {
            int cnt = unstCnt[blk];
            for (int j = t; j < cnt; j += 256) {
                int f = unstList[(size_t)blk * CHUNKF + j];
                int i0 = faces[3*f+0], i1 = faces[3*f+1], i2 = faces[3*f+2];
                float w0, w1, w2, w3;
                face_math(mesh, cano, i0, i1, i2, w0, w1, w2, w3);
                int tg[3] = {i0, i1, i2};
                #pragma unroll
                for (int k = 0; k < 3; ++k) {
                    int v = tg[k];
                    if (v >= base && v < base + BS && v < V) {
                        atomicAdd(&Ew[v - base][0], w0);
                        atomicAdd(&Ew[v - base][1], w1);
                        atomicAdd(&Ew[v - base][2], w2);
                        atomicAdd(&Ew[v - base][3], w3);
                    }
                }
            }
        }
        __syncthreads();
    }

    int v = base + t;
    if (t < rows) {
        float4 a4 = Tw[t + 2], b4 = Tw[t + 1], c4 = Tw[t];
        float ex = 0.f, ey = 0.f, ez = 0.f, ew = 0.f;
        if (anyU) { ex = Ew[t][0]; ey = Ew[t][1]; ez = Ew[t][2]; ew = Ew[t][3]; }
        float x = a4.x + b4.x + c4.x + ex;
        float y = a4.y + b4.y + c4.y + ey;
        float z = a4.z + b4.z + c4.z + ez;
        float w = a4.w + b4.w + c4.w + ew;
        float n2 = x * x + y * y + z * z + w * w;
        // q / max(||q||, 1e-6): normal case rsqrt; tiny case q * 1e6
        float inv = (n2 > 1e-12f) ? fast_rsqrt(n2) : 1e6f;
        reinterpret_cast<float4*>(out)[v] = make_float4(x * inv, y * inv, z * inv, w * inv);
    }
}

// ================= fallback paths (share fast face_core) ====================
typedef _Float16 hf2 __attribute__((ext_vector_type(2)));

__device__ __forceinline__ void atomic_pk_add_f16(__half* base, float a, float b) {
#if __has_builtin(__builtin_amdgcn_global_atomic_fadd_v2f16)
    hf2 v; v.x = (_Float16)a; v.y = (_Float16)b;
    __builtin_amdgcn_global_atomic_fadd_v2f16(
        (__attribute__((address_space(1))) hf2*)base, v);
#else
    union { _Float16 h[2]; unsigned int u; } pk;
    pk.h[0] = (_Float16)a; pk.h[1] = (_Float16)b;
    asm volatile("global_atomic_pk_add_f16 %0, %1, off"
                 :: "v"(base), "v"(pk.u) : "memory");
#endif
}

__global__ void face_kernel_f16(const float* __restrict__ mesh,
                                const float* __restrict__ cano,
                                const int* __restrict__ faces,
                                __half* __restrict__ T, float* __restrict__ E,
                                int F, int V) {
    int f = blockIdx.x * blockDim.x + threadIdx.x;
    if (f >= F) return;
    int i0 = faces[3*f+0], i1 = faces[3*f+1], i2 = faces[3*f+2];
    float w0, w1, w2, w3;
    face_math(mesh, cano, i0, i1, i2, w0, w1, w2, w3);
    if (is_structured(i0, i1, i2, V)) {
        __half* t = T + 4 * (size_t)i0;
        atomic_pk_add_f16(t,     w0, w1);
        atomic_pk_add_f16(t + 2, w2, w3);
    } else {
        atomicAdd(&E[4*i0+0], w0); atomicAdd(&E[4*i0+1], w1);
        atomicAdd(&E[4*i0+2], w2); atomicAdd(&E[4*i0+3], w3);
        atomicAdd(&E[4*i1+0], w0); atomicAdd(&E[4*i1+1], w1);
        atomicAdd(&E[4*i1+2], w2); atomicAdd(&E[4*i1+3], w3);
        atomicAdd(&E[4*i2+0], w0); atomicAdd(&E[4*i2+1], w1);
        atomicAdd(&E[4*i2+2], w2); atomicAdd(&E[4*i2+3], w3);
    }
}

__global__ void finish_kernel_f16(const __half* __restrict__ T,
                                  const float* __restrict__ E,
                                  float* __restrict__ out, int V) {
    int v = blockIdx.x * blockDim.x + threadIdx.x;
    if (v >= V) return;
    int vm1 = (v >= 1) ? v - 1 : v - 1 + V;
    int vm2 = (v >= 2) ? v - 2 : v - 2 + V;
    const __half2* p0 = reinterpret_cast<const __half2*>(T + 4 * (size_t)v);
    const __half2* p1 = reinterpret_cast<const __half2*>(T + 4 * (size_t)vm1);
    const __half2* p2 = reinterpret_cast<const __half2*>(T + 4 * (size_t)vm2);
    float2 a01 = __half22float2(p0[0]), a23 = __half22float2(p0[1]);
    float2 b01 = __half22float2(p1[0]), b23 = __half22float2(p1[1]);
    float2 c01 = __half22float2(p2[0]), c23 = __half22float2(p2[1]);
    float4 e = reinterpret_cast<const float4*>(E)[v];
    float x = a01.x + b01.x + c01.x + e.x;
    float y = a01.y + b01.y + c01.y + e.y;
    float z = a23.x + b23.x + c23.x + e.z;
    float w = a23.y + b23.y + c23.y + e.w;
    float n = sqrtf(x * x + y * y + z * z + w * w);
    float inv = 1.0f / fmaxf(n, 1e-6f);
    reinterpret_cast<float4*>(out)[v] = make_float4(x * inv, y * inv, z * inv, w * inv);
}

__global__ void face_kernel_direct(const float* __restrict__ mesh,
                                   const float* __restrict__ cano,
                                   const int* __restrict__ faces,
                                   float* __restrict__ out, int F) {
    int f = blockIdx.x * blockDim.x + threadIdx.x;
    if (f >= F) return;
    int i0 = faces[3*f+0], i1 = faces[3*f+1], i2 = faces[3*f+2];
    float w0, w1, w2, w3;
    face_math(mesh, cano, i0, i1, i2, w0, w1, w2, w3);
    atomicAdd(&out[4*i0+0], w0); atomicAdd(&out[4*i0+1], w1);
    atomicAdd(&out[4*i0+2], w2); atomicAdd(&out[4*i0+3], w3);
    atomicAdd(&out[4*i1+0], w0); atomicAdd(&out[4*i1+1], w1);
    atomicAdd(&out[4*i1+2], w2); atomicAdd(&out[4*i1+3], w3);
    atomicAdd(&out[4*i2+0], w0); atomicAdd(&out[4*i2+1], w1);
    atomicAdd(&out[4*i2+2], w2); atomicAdd(&out[4*i2+3], w3);
}

__global__ void norm_kernel(float* __restrict__ out, int V) {
    int v = blockIdx.x * blockDim.x + threadIdx.x;
    if (v >= V) return;
    float4 q = reinterpret_cast<float4*>(out)[v];
    float n = sqrtf(q.x*q.x + q.y*q.y + q.z*q.z + q.w*q.w);
    float inv = 1.0f / fmaxf(n, 1e-6f);
    reinterpret_cast<float4*>(out)[v] = make_float4(q.x*inv, q.y*inv, q.z*inv, q.w*inv);
}

extern "C" void kernel_launch(void* const* d_in, const int* in_sizes, int n_in,
                              void* d_out, int out_size, void* d_ws, size_t ws_size,
                              hipStream_t stream) {
    const float* mesh  = (const float*)d_in[0];
    const float* cano  = (const float*)d_in[1];
    const int*   faces = (const int*)d_in[2];
    float* out = (float*)d_out;

    int V = in_sizes[0] / 3;
    int F = in_sizes[2] / 3;
    const int TB = 256;
    int NB = (V + BS - 1) / BS;
    int CHUNKF = (F + NBLK1 - 1) / NBLK1;

    size_t bHoff  = (size_t)NBLK1 * NBMAX * 4;
    size_t bHoffT = (size_t)NBMAX * NBLK1 * 4;
    size_t bS1    = (((size_t)NBLK1 * CHUNKF) + 15) & ~15ull;
    size_t bUC    = (size_t)NBLK1 * 4;
    size_t bUL    = (size_t)NBLK1 * CHUNKF * 4;
    size_t needFull = bHoff + bHoffT + bS1 + bUC + bUL;

    size_t bytesTf16 = (size_t)V * 4 * sizeof(__half);
    size_t bytesEf32 = (size_t)V * 4 * sizeof(float);

    if (ws_size >= needFull && NB <= NBMAX && CHUNKF <= CHMAX) {
        char* p = (char*)d_ws;
        unsigned int*  Hoff    = (unsigned int*)p;   p += bHoff;
        unsigned int*  HoffT   = (unsigned int*)p;   p += bHoffT;
        unsigned char* S1      = (unsigned char*)p;  p += bS1;
        int*           unstCnt = (int*)p;            p += bUC;
        int*           unstList = (int*)p;

        sort_kernel<<<NBLK1, 1024, 0, stream>>>(faces, Hoff, S1, unstCnt, unstList,
                                                F, V, NB, CHUNKF);
        dim3 tgrid((NB + 63) / 64, NBLK1 / 64);
        transpose_kernel<<<tgrid, dim3(64, 16), 0, stream>>>(Hoff, HoffT, NB);
        countfinish_kernel<<<NB, 256, 0, stream>>>(mesh, cano, HoffT, S1,
                                                   unstCnt, unstList, faces,
                                                   out, V, NB, CHUNKF);
    } else if (ws_size >= bytesTf16 + bytesEf32) {
        __half* T = (__half*)d_ws;
        float*  E = (float*)((char*)d_ws + bytesTf16);
        (void)hipMemsetAsync(d_ws, 0, bytesTf16 + bytesEf32, stream);
        face_kernel_f16<<<(F + TB - 1) / TB, TB, 0, stream>>>(mesh, cano, faces, T, E, F, V);
        finish_kernel_f16<<<(V + TB - 1) / TB, TB, 0, stream>>>(T, E, out, V);
    } else {
        (void)hipMemsetAsync(out, 0, (size_t)V * 4 * sizeof(float), stream);
        face_kernel_direct<<<(F + TB - 1) / TB, TB, 0, stream>>>(mesh, cano, faces, out, F);
        norm_kernel<<<(V + TB - 1) / TB, TB, 0, stream>>>(out, V);
    }
}

// Round 18
// 32.776 us; speedup vs baseline: 1.0510x; 1.0510x over previous
//
#include <hip/hip_runtime.h>
#include <hip/hip_fp16.h>
#include <math.h>

// PerVertQuaternion, round 18: revert to R16 (best: 32.8us), cleaned.
//
// R17 post-mortem: merging count into finish regressed (+1.6us) -- the
// boundary-row descriptor walks tripled scan work vs one saved dispatch.
// R16's 4-dispatch split is the local optimum:
//   sort      (512 blk x 1024): LDS histogram + prefix + residue-byte
//             scatter into block-owned S1 chunks; Hoff[chunk][bucket].
//   transpose Hoff -> HoffT (coalesced 64x64 tiles).
//   count     (block = bucket): contiguous HoffT row + S1 run walk ->
//             LDS counters -> coalesced cntA write.
//   finish    (block = 256 rows): dedup'd count*w (fast math: 2 rsqrt per
//             frame, 1 quaternion sqrt, free area), window sum, normalize.
//
// Session laws (earned over 17 rounds):
//  * scattered global WRITES catastrophic: ~19.3G 32B-sector RMWs/s,
//    cross-XCD write-through; atomic count is THE scatter cost metric.
//  * scattered global READS cheap when L2/L3-resident.
//  * faces sharing i0 are identical triangles -> dedup: count[i0] * w(i0).
//  * rocclr memset slow for MB-scale buffers (use own zero kernel).
//  * grid.sync ~30us on 8 XCDs -- kernel boundaries are cheaper.
//  * precise sqrt/div = ~10-op sequences; native v_rsq/v_rcp/v_sqrt when
//    tolerance (2e-2 here) allows.
//  * fusing phases that change data axis (chunk-major <-> bucket-major)
//    re-introduces scattered walks; keep the transpose.

#define BS     256     // bases per bucket
#define NBMAX  2048    // max buckets (V <= 524288)
#define NBLK1  512     // sort chunks
#define CHMAX  2048    // max faces per chunk (F <= 1,048,576)

__device__ __forceinline__ float fast_rsqrt(float x) {
#if __has_builtin(__builtin_amdgcn_rsqf)
    return __builtin_amdgcn_rsqf(x);
#else
    return rsqrtf(x);
#endif
}
__device__ __forceinline__ float fast_rcp(float x) {
#if __has_builtin(__builtin_amdgcn_rcpf)
    return __builtin_amdgcn_rcpf(x);
#else
    return 1.0f / x;
#endif
}
__device__ __forceinline__ float fast_sqrt(float x) {
#if __has_builtin(__builtin_amdgcn_sqrtf)
    return __builtin_amdgcn_sqrtf(x);
#else
    return sqrtf(x);
#endif
}

struct V3 { float x, y, z; };

__device__ __forceinline__ V3 v3sub(const V3& a, const V3& b) {
    return V3{a.x - b.x, a.y - b.y, a.z - b.z};
}
__device__ __forceinline__ V3 v3cross(const V3& a, const V3& b) {
    return V3{a.y * b.z - a.z * b.y,
              a.z * b.x - a.x * b.z,
              a.x * b.y - a.y * b.x};
}
__device__ __forceinline__ float v3dot(const V3& a, const V3& b) {
    return a.x * b.x + a.y * b.y + a.z * b.z;
}
__device__ __forceinline__ V3 loadv(const float* __restrict__ p, int i) {
    return V3{p[3 * i], p[3 * i + 1], p[3 * i + 2]};
}

// Orthonormal frame via n ⟂ d / X ⟂ d algebra; returns n2 for area reuse.
__device__ __forceinline__ float frame_fast(V3 a, V3 b, V3 c,
                                            V3& X, V3& Y, V3& Z) {
    V3 d = v3sub(b, a);
    V3 e = v3sub(c, a);
    V3 n = v3cross(d, e);
    float n2 = v3dot(n, n);
    float d2 = v3dot(d, d);
    float inv_d = fast_rsqrt(fmaxf(d2, 1e-24f));
    float inv_n = fast_rsqrt(fmaxf(n2, 1e-24f));
    V3 cdn = v3cross(d, n);
    float sX = inv_n * inv_d;           // |cross(d, n_hat)| == |d|
    X = V3{cdn.x * sX, cdn.y * sX, cdn.z * sX};
    V3 cdx = v3cross(d, X);             // |cross(d, X)| == |d|
    Y = V3{cdx.x * inv_d, cdx.y * inv_d, cdx.z * inv_d};
    Z = V3{d.x * inv_d, d.y * inv_d, d.z * inv_d};
    return n2;
}

__device__ __forceinline__ void face_core(V3 ca, V3 cb, V3 cc,
                                          V3 da, V3 db, V3 dc,
                                          float& w0, float& w1, float& w2, float& w3) {
    V3 Xc, Yc, Zc, Xd, Yd, Zd;
    float n2c = frame_fast(ca, cb, cc, Xc, Yc, Zc);
    (void)frame_fast(da, db, dc, Xd, Yd, Zd);

    // area = |cross(cc-cb,ca-cb)|/2 == |cross(cb-ca,cc-ca)|/2 = sqrt(n2c)/2
    float area = 0.5f * fast_sqrt(n2c);

    // Rot = R_deform * R_cano^T (orthonormal frames -> inv == transpose)
    float Rd[3][3] = {{Xd.x, Yd.x, Zd.x}, {Xd.y, Yd.y, Zd.y}, {Xd.z, Yd.z, Zd.z}};
    float Rc[3][3] = {{Xc.x, Yc.x, Zc.x}, {Xc.y, Yc.y, Zc.y}, {Xc.z, Yc.z, Zc.z}};
    float m00 = Rd[0][0]*Rc[0][0] + Rd[0][1]*Rc[0][1] + Rd[0][2]*Rc[0][2];
    float m01 = Rd[0][0]*Rc[1][0] + Rd[0][1]*Rc[1][1] + Rd[0][2]*Rc[1][2];
    float m02 = Rd[0][0]*Rc[2][0] + Rd[0][1]*Rc[2][1] + Rd[0][2]*Rc[2][2];
    float m10 = Rd[1][0]*Rc[0][0] + Rd[1][1]*Rc[0][1] + Rd[1][2]*Rc[0][2];
    float m11 = Rd[1][0]*Rc[1][0] + Rd[1][1]*Rc[1][1] + Rd[1][2]*Rc[1][2];
    float m12 = Rd[1][0]*Rc[2][0] + Rd[1][1]*Rc[2][1] + Rd[1][2]*Rc[2][2];
    float m20 = Rd[2][0]*Rc[0][0] + Rd[2][1]*Rc[0][1] + Rd[2][2]*Rc[0][2];
    float m21 = Rd[2][0]*Rc[1][0] + Rd[2][1]*Rc[1][1] + Rd[2][2]*Rc[1][2];
    float m22 = Rd[2][0]*Rc[2][0] + Rd[2][1]*Rc[2][1] + Rd[2][2]*Rc[2][2];

    // argmax over qa == argmax over t; qa_best^2 == t_best -> ONE sqrt.
    float t0 = 1.0f + m00 + m11 + m22;
    float t1 = 1.0f + m00 - m11 - m22;
    float t2 = 1.0f - m00 + m11 - m22;
    float t3 = 1.0f - m00 - m11 + m22;
    int best = 0; float tb = t0;
    if (t1 > tb) { best = 1; tb = t1; }
    if (t2 > tb) { best = 2; tb = t2; }
    if (t3 > tb) { best = 3; tb = t3; }
    float qb = fast_sqrt(tb);

    float q0, q1, q2, q3;
    if (best == 0)      { q0 = tb;      q1 = m21-m12; q2 = m02-m20; q3 = m10-m01; }
    else if (best == 1) { q0 = m21-m12; q1 = tb;      q2 = m10+m01; q3 = m02+m20; }
    else if (best == 2) { q0 = m02-m20; q1 = m10+m01; q2 = tb;      q3 = m12+m21; }
    else                { q0 = m10-m01; q1 = m20+m02; q2 = m21+m12; q3 = tb;      }
    float scale = area * 0.5f * fast_rcp(fmaxf(qb, 0.1f));
    w0 = q0 * scale; w1 = q1 * scale; w2 = q2 * scale; w3 = q3 * scale;
}

__device__ __forceinline__ void face_math(const float* __restrict__ mesh,
                                          const float* __restrict__ cano,
                                          int i0, int i1, int i2,
                                          float& w0, float& w1, float& w2, float& w3) {
    face_core(loadv(cano, i0), loadv(cano, i1), loadv(cano, i2),
              loadv(mesh, i0), loadv(mesh, i1), loadv(mesh, i2),
              w0, w1, w2, w3);
}

__device__ __forceinline__ bool is_structured(int i0, int i1, int i2, int V) {
    int e1 = (i0 + 1 < V) ? i0 + 1 : i0 + 1 - V;
    int e2 = (i0 + 2 < V) ? i0 + 2 : i0 + 2 - V;
    return (i1 == e1) & (i2 == e2);
}

// ---------------- P1: counting sort -> residue bytes, block-major -----------
__global__ __launch_bounds__(1024)
void sort_kernel(const int* __restrict__ faces,
                 unsigned int* __restrict__ Hoff,      // [NBLK1][NBMAX] off|cnt<<16
                 unsigned char* __restrict__ S1,       // [NBLK1][CHUNKF] residues
                 int* __restrict__ unstCnt,            // [NBLK1]
                 int* __restrict__ unstList,           // [NBLK1][CHUNKF]
                 int F, int V, int NB, int CHUNKF) {
    __shared__ int h[NBMAX];
    __shared__ int off[NBMAX];
    __shared__ int cnt2[NBMAX];
    __shared__ int S0[CHMAX];
    __shared__ int wsum[16];
    __shared__ int unstC;

    int tid = threadIdx.x;
    for (int b = tid; b < NB; b += 1024) { h[b] = 0; cnt2[b] = 0; }
    if (tid == 0) unstC = 0;
    __syncthreads();

    int beg = blockIdx.x * CHUNKF;
    int end = min(F, beg + CHUNKF);

    for (int f = beg + tid; f < end; f += 1024) {
        int i0 = faces[3 * f + 0];
        int i1 = faces[3 * f + 1];
        int i2 = faces[3 * f + 2];
        if (is_structured(i0, i1, i2, V)) {
            S0[f - beg] = i0;
            atomicAdd(&h[i0 >> 8], 1);
        } else {
            S0[f - beg] = -1;
            int p = atomicAdd(&unstC, 1);
            unstList[(size_t)blockIdx.x * CHUNKF + p] = f;
        }
    }
    __syncthreads();

    {
        int e0 = (2 * tid < NB)     ? h[2 * tid]     : 0;
        int e1 = (2 * tid + 1 < NB) ? h[2 * tid + 1] : 0;
        int mysum = e0 + e1;
        int lane = tid & 63, wid = tid >> 6;
        int inc = mysum;
        #pragma unroll
        for (int d = 1; d < 64; d <<= 1) {
            int up = __shfl_up(inc, d);
            if (lane >= d) inc += up;
        }
        if (lane == 63) wsum[wid] = inc;
        __syncthreads();
        if (tid == 0) {
            int run = 0;
            #pragma unroll
            for (int i = 0; i < 16; ++i) { int x = wsum[i]; wsum[i] = run; run += x; }
        }
        __syncthreads();
        int excl = wsum[wid] + inc - mysum;
        if (2 * tid < NBMAX)     off[2 * tid]     = excl;
        if (2 * tid + 1 < NBMAX) off[2 * tid + 1] = excl + e0;
    }
    __syncthreads();

    for (int b = tid; b < NB; b += 1024)
        Hoff[(size_t)blockIdx.x * NBMAX + b] =
            (unsigned int)off[b] | ((unsigned int)h[b] << 16);
    if (tid == 0) unstCnt[blockIdx.x] = unstC;

    unsigned char* S1blk = S1 + (size_t)blockIdx.x * CHUNKF;
    for (int j = tid; j < end - beg; j += 1024) {
        int i0 = S0[j];
        if (i0 >= 0) {
            int b = i0 >> 8;
            int p = atomicAdd(&cnt2[b], 1);
            S1blk[off[b] + p] = (unsigned char)(i0 & 0xFF);
        }
    }
}

// ---------------- P2: tiled transpose Hoff -> HoffT -------------------------
__global__ __launch_bounds__(1024)
void transpose_kernel(const unsigned int* __restrict__ Hoff,
                      unsigned int* __restrict__ HoffT, int NB) {
    __shared__ unsigned int tile[64][65];
    int bx = blockIdx.x * 64;
    int by = blockIdx.y * 64;
    int tx = threadIdx.x;
    int ty = threadIdx.y;
    #pragma unroll
    for (int k = 0; k < 4; ++k) {
        int r = by + ty + k * 16;
        int c = bx + tx;
        tile[ty + k * 16][tx] = (c < NB) ? Hoff[(size_t)r * NBMAX + c] : 0u;
    }
    __syncthreads();
    #pragma unroll
    for (int k = 0; k < 4; ++k) {
        int rowT = bx + ty + k * 16;
        int colT = by + tx;
        if (rowT < NB)
            HoffT[(size_t)rowT * NBLK1 + colT] = tile[tx][ty + k * 16];
    }
}

// ---------------- P3: per-bucket residue counting -> cntA[v] ----------------
__global__ __launch_bounds__(256)
void count_kernel(const unsigned int* __restrict__ HoffT,
                  const unsigned char* __restrict__ S1,
                  unsigned int* __restrict__ cntA,
                  int V, int NB, int CHUNKF) {
    int b = blockIdx.x;
    if (b >= NB) return;
    __shared__ unsigned int cnt_l[BS];
    cnt_l[threadIdx.x] = 0;
    __syncthreads();
    for (int r = threadIdx.x; r < NBLK1; r += 256) {
        unsigned int pc = HoffT[(size_t)b * NBLK1 + r];
        int start = (int)(pc & 0xFFFFu);
        int cnt   = (int)(pc >> 16);
        const unsigned char* run = S1 + (size_t)r * CHUNKF + start;
        for (int j = 0; j < cnt; ++j)
            atomicAdd(&cnt_l[run[j]], 1u);
    }
    __syncthreads();
    int row = b * BS + (int)threadIdx.x;
    if (row < V) cntA[row] = cnt_l[threadIdx.x];
}

// ---------------- P4: fused math + window sum + normalize -------------------
__global__ __launch_bounds__(256)
void finish_kernel(const float* __restrict__ mesh,
                   const float* __restrict__ cano,
                   const unsigned int* __restrict__ cntA,
                   const int* __restrict__ unstCnt,
                   const int* __restrict__ unstList,
                   const int* __restrict__ faces,
                   float* __restrict__ out, int V, int CHUNKF) {
    __shared__ float4 Tw[BS + 2];
    __shared__ float Ew[BS][4];
    __shared__ int anyU;
    int base = blockIdx.x * BS;
    int t = threadIdx.x;

    if (t == 0) anyU = 0;
    __syncthreads();
    {
        int u = unstCnt[t] | unstCnt[t + 256];
        if (u) atomicOr(&anyU, 1);
    }

    for (int j = t; j < BS + 2; j += 256) {
        int row = base - 2 + j;
        if (row < 0) row += V;
        if (row >= V) row -= V;
        unsigned int c = cntA[row];
        float4 res = make_float4(0.f, 0.f, 0.f, 0.f);
        if (c > 0) {
            int i1 = (row + 1 < V) ? row + 1 : row + 1 - V;
            int i2 = (row + 2 < V) ? row + 2 : row + 2 - V;
            float w0, w1, w2, w3;
            face_math(mesh, cano, row, i1, i2, w0, w1, w2, w3);
            float fc = (float)c;
            res = make_float4(w0 * fc, w1 * fc, w2 * fc, w3 * fc);
        }
        Tw[j] = res;
    }
    __syncthreads();

    if (anyU) {
        Ew[t][0] = Ew[t][1] = Ew[t][2] = Ew[t][3] = 0.f;
        __syncthreads();
        for (int blk = 0; blk < NBLK1; ++blk) {
            int cnt = unstCnt[blk];
            for (int j = t; j < cnt; j += 256) {
                int f = unstList[(size_t)blk * CHUNKF + j];
                int i0 = faces[3*f+0], i1 = faces[3*f+1], i2 = faces[3*f+2];
                float w0, w1, w2, w3;
                face_math(mesh, cano, i0, i1, i2, w0, w1, w2, w3);
                int tg[3] = {i0, i1, i2};
                #pragma unroll
                for (int k = 0; k < 3; ++k) {
                    int v = tg[k];
                    if (v >= base && v < base + BS && v < V) {
                        atomicAdd(&Ew[v - base][0], w0);
                        atomicAdd(&Ew[v - base][1], w1);
                        atomicAdd(&Ew[v - base][2], w2);
                        atomicAdd(&Ew[v - base][3], w3);
                    }
                }
            }
        }
        __syncthreads();
    }

    int v = base + t;
    if (v < V) {
        float4 a = Tw[t + 2], b4 = Tw[t + 1], c4 = Tw[t];
        float ex = 0.f, ey = 0.f, ez = 0.f, ew = 0.f;
        if (anyU) { ex = Ew[t][0]; ey = Ew[t][1]; ez = Ew[t][2]; ew = Ew[t][3]; }
        float x = a.x + b4.x + c4.x + ex;
        float y = a.y + b4.y + c4.y + ey;
        float z = a.z + b4.z + c4.z + ez;
        float w = a.w + b4.w + c4.w + ew;
        float n2 = x * x + y * y + z * z + w * w;
        // q / max(||q||, 1e-6): normal case rsqrt(n2); tiny case q * 1e6
        float inv = (n2 > 1e-12f) ? fast_rsqrt(n2) : 1e6f;
        reinterpret_cast<float4*>(out)[v] = make_float4(x * inv, y * inv, z * inv, w * inv);
    }
}

// ================= fallback paths (share fast face_core) ====================
typedef _Float16 hf2 __attribute__((ext_vector_type(2)));

__device__ __forceinline__ void atomic_pk_add_f16(__half* base, float a, float b) {
#if __has_builtin(__builtin_amdgcn_global_atomic_fadd_v2f16)
    hf2 v; v.x = (_Float16)a; v.y = (_Float16)b;
    __builtin_amdgcn_global_atomic_fadd_v2f16(
        (__attribute__((address_space(1))) hf2*)base, v);
#else
    union { _Float16 h[2]; unsigned int u; } pk;
    pk.h[0] = (_Float16)a; pk.h[1] = (_Float16)b;
    asm volatile("global_atomic_pk_add_f16 %0, %1, off"
                 :: "v"(base), "v"(pk.u) : "memory");
#endif
}

__global__ void face_kernel_f16(const float* __restrict__ mesh,
                                const float* __restrict__ cano,
                                const int* __restrict__ faces,
                                __half* __restrict__ T, float* __restrict__ E,
                                int F, int V) {
    int f = blockIdx.x * blockDim.x + threadIdx.x;
    if (f >= F) return;
    int i0 = faces[3*f+0], i1 = faces[3*f+1], i2 = faces[3*f+2];
    float w0, w1, w2, w3;
    face_math(mesh, cano, i0, i1, i2, w0, w1, w2, w3);
    if (is_structured(i0, i1, i2, V)) {
        __half* t = T + 4 * (size_t)i0;
        atomic_pk_add_f16(t,     w0, w1);
        atomic_pk_add_f16(t + 2, w2, w3);
    } else {
        atomicAdd(&E[4*i0+0], w0); atomicAdd(&E[4*i0+1], w1);
        atomicAdd(&E[4*i0+2], w2); atomicAdd(&E[4*i0+3], w3);
        atomicAdd(&E[4*i1+0], w0); atomicAdd(&E[4*i1+1], w1);
        atomicAdd(&E[4*i1+2], w2); atomicAdd(&E[4*i1+3], w3);
        atomicAdd(&E[4*i2+0], w0); atomicAdd(&E[4*i2+1], w1);
        atomicAdd(&E[4*i2+2], w2); atomicAdd(&E[4*i2+3], w3);
    }
}

__global__ void finish_kernel_f16(const __half* __restrict__ T,
                                  const float* __restrict__ E,
                                  float* __restrict__ out, int V) {
    int v = blockIdx.x * blockDim.x + threadIdx.x;
    if (v >= V) return;
    int vm1 = (v >= 1) ? v - 1 : v - 1 + V;
    int vm2 = (v >= 2) ? v - 2 : v - 2 + V;
    const __half2* p0 = reinterpret_cast<const __half2*>(T + 4 * (size_t)v);
    const __half2* p1 = reinterpret_cast<const __half2*>(T + 4 * (size_t)vm1);
    const __half2* p2 = reinterpret_cast<const __half2*>(T + 4 * (size_t)vm2);
    float2 a01 = __half22float2(p0[0]), a23 = __half22float2(p0[1]);
    float2 b01 = __half22float2(p1[0]), b23 = __half22float2(p1[1]);
    float2 c01 = __half22float2(p2[0]), c23 = __half22float2(p2[1]);
    float4 e = reinterpret_cast<const float4*>(E)[v];
    float x = a01.x + b01.x + c01.x + e.x;
    float y = a01.y + b01.y + c01.y + e.y;
    float z = a23.x + b23.x + c23.x + e.z;
    float w = a23.y + b23.y + c23.y + e.w;
    float n = sqrtf(x * x + y * y + z * z + w * w);
    float inv = 1.0f / fmaxf(n, 1e-6f);
    reinterpret_cast<float4*>(out)[v] = make_float4(x * inv, y * inv, z * inv, w * inv);
}

__global__ void face_kernel_direct(const float* __restrict__ mesh,
                                   const float* __restrict__ cano,
                                   const int* __restrict__ faces,
                                   float* __restrict__ out, int F) {
    int f = blockIdx.x * blockDim.x + threadIdx.x;
    if (f >= F) return;
    int i0 = faces[3*f+0], i1 = faces[3*f+1], i2 = faces[3*f+2];
    float w0, w1, w2, w3;
    face_math(mesh, cano, i0, i1, i2, w0, w1, w2, w3);
    atomicAdd(&out[4*i0+0], w0); atomicAdd(&out[4*i0+1], w1);
    atomicAdd(&out[4*i0+2], w2); atomicAdd(&out[4*i0+3], w3);
    atomicAdd(&out[4*i1+0], w0); atomicAdd(&out[4*i1+1], w1);
    atomicAdd(&out[4*i1+2], w2); atomicAdd(&out[4*i1+3], w3);
    atomicAdd(&out[4*i2+0], w0); atomicAdd(&out[4*i2+1], w1);
    atomicAdd(&out[4*i2+2], w2); atomicAdd(&out[4*i2+3], w3);
}

__global__ void norm_kernel(float* __restrict__ out, int V) {
    int v = blockIdx.x * blockDim.x + threadIdx.x;
    if (v >= V) return;
    float4 q = reinterpret_cast<float4*>(out)[v];
    float n = sqrtf(q.x*q.x + q.y*q.y + q.z*q.z + q.w*q.w);
    float inv = 1.0f / fmaxf(n, 1e-6f);
    reinterpret_cast<float4*>(out)[v] = make_float4(q.x*inv, q.y*inv, q.z*inv, q.w*inv);
}

extern "C" void kernel_launch(void* const* d_in, const int* in_sizes, int n_in,
                              void* d_out, int out_size, void* d_ws, size_t ws_size,
                              hipStream_t stream) {
    const float* mesh  = (const float*)d_in[0];
    const float* cano  = (const float*)d_in[1];
    const int*   faces = (const int*)d_in[2];
    float* out = (float*)d_out;

    int V = in_sizes[0] / 3;
    int F = in_sizes[2] / 3;
    const int TB = 256;
    int NB = (V + BS - 1) / BS;
    int CHUNKF = (F + NBLK1 - 1) / NBLK1;

    size_t bHoff  = (size_t)NBLK1 * NBMAX * 4;
    size_t bHoffT = (size_t)NBMAX * NBLK1 * 4;
    size_t bS1    = (((size_t)NBLK1 * CHUNKF) + 15) & ~15ull;
    size_t bCnt   = (size_t)V * 4;
    size_t bUC    = (size_t)NBLK1 * 4;
    size_t bUL    = (size_t)NBLK1 * CHUNKF * 4;
    size_t needFull = bHoff + bHoffT + bS1 + bCnt + bUC + bUL;

    size_t bytesTf16 = (size_t)V * 4 * sizeof(__half);
    size_t bytesEf32 = (size_t)V * 4 * sizeof(float);

    if (ws_size >= needFull && NB <= NBMAX && CHUNKF <= CHMAX) {
        char* p = (char*)d_ws;
        unsigned int*  Hoff    = (unsigned int*)p;   p += bHoff;
        unsigned int*  HoffT   = (unsigned int*)p;   p += bHoffT;
        unsigned char* S1      = (unsigned char*)p;  p += bS1;
        unsigned int*  cntA    = (unsigned int*)p;   p += bCnt;
        int*           unstCnt = (int*)p;            p += bUC;
        int*           unstList = (int*)p;

        sort_kernel<<<NBLK1, 1024, 0, stream>>>(faces, Hoff, S1, unstCnt, unstList,
                                                F, V, NB, CHUNKF);
        dim3 tgrid((NB + 63) / 64, NBLK1 / 64);
        transpose_kernel<<<tgrid, dim3(64, 16), 0, stream>>>(Hoff, HoffT, NB);
        count_kernel<<<NB, 256, 0, stream>>>(HoffT, S1, cntA, V, NB, CHUNKF);
        finish_kernel<<<NB, 256, 0, stream>>>(mesh, cano, cntA, unstCnt, unstList,
                                              faces, out, V, CHUNKF);
    } else if (ws_size >= bytesTf16 + bytesEf32) {
        __half* T = (__half*)d_ws;
        float*  E = (float*)((char*)d_ws + bytesTf16);
        (void)hipMemsetAsync(d_ws, 0, bytesTf16 + bytesEf32, stream);
        face_kernel_f16<<<(F + TB - 1) / TB, TB, 0, stream>>>(mesh, cano, faces, T, E, F, V);
        finish_kernel_f16<<<(V + TB - 1) / TB, TB, 0, stream>>>(T, E, out, V);
    } else {
        (void)hipMemsetAsync(out, 0, (size_t)V * 4 * sizeof(float), stream);
        face_kernel_direct<<<(F + TB - 1) / TB, TB, 0, stream>>>(mesh, cano, faces, out, F);
        norm_kernel<<<(V + TB - 1) / TB, TB, 0, stream>>>(out, V);
    }
}